// Round 8
// baseline (174.989 us; speedup 1.0000x reference)
//
#include <hip/hip_runtime.h>
#include <math.h>
#include <stdint.h>

#define BB 8
#define NN 16384
#define CC 80
#define TT 100
#define CAP 1024
#define MMAX 256                 // fast-path candidate cap
#define BAND_LO 0.98828125f      // 1 - 3/256
#define BASEBITS 0x3F7D0000u     // __float_as_uint(BAND_LO)
#define LCAP 24                  // per-slice per-class cap (E=3)
#define SLICES 64
#define ROWS 256                 // NN / SLICES

typedef unsigned int u32;
typedef unsigned long long u64;

__device__ __forceinline__ u64 shfl_xor_u64(u64 v, int m) {
  int lo = __shfl_xor((int)(u32)v, m);
  int hi = __shfl_xor((int)(v >> 32), m);
  return ((u64)(u32)hi << 32) | (u32)lo;
}

// plain LDS bitonic (descending), 256 threads, any pow2 n2
__device__ __forceinline__ void bitonic_desc64(u64* buf, int n2, int tid) {
  for (int k = 2; k <= n2; k <<= 1)
    for (int j = k >> 1; j > 0; j >>= 1) {
      for (int i = tid; i < n2; i += 256) {
        int ixj = i ^ j;
        if (ixj > i) {
          u64 a = buf[i], d2 = buf[ixj];
          bool up = ((i & k) == 0);
          if (up ? (a < d2) : (a > d2)) { buf[i] = d2; buf[ixj] = a; }
        }
      }
      __syncthreads();
    }
}

// hybrid shfl/LDS bitonic over exactly 256 elements, 256 threads (descending)
__device__ __forceinline__ void hybrid_sort256_u64(u64* buf, int tid) {
  u64 r = buf[tid];
  for (int k = 2; k <= 256; k <<= 1)
    for (int j = k >> 1; j > 0; j >>= 1) {
      int keep_max = (((tid & k) == 0) == ((tid & j) == 0));
      u64 other;
      if (j >= 64) { __syncthreads(); buf[tid] = r; __syncthreads(); other = buf[tid ^ j]; }
      else other = shfl_xor_u64(r, j);
      u64 mx = (r > other) ? r : other, mn = (r > other) ? other : r;
      r = keep_max ? mx : mn;
    }
  __syncthreads(); buf[tid] = r; __syncthreads();
}

__device__ __forceinline__ void hybrid_sort256_u32(u32* buf, int tid) {
  u32 r = buf[tid];
  for (int k = 2; k <= 256; k <<= 1)
    for (int j = k >> 1; j > 0; j >>= 1) {
      int keep_max = (((tid & k) == 0) == ((tid & j) == 0));
      u32 other;
      if (j >= 64) { __syncthreads(); buf[tid] = r; __syncthreads(); other = buf[tid ^ j]; }
      else other = __shfl_xor(r, j);
      u32 mx = (r > other) ? r : other, mn = (r > other) ? other : r;
      r = keep_max ? mx : mn;
    }
  __syncthreads(); buf[tid] = r; __syncthreads();
}

// ---------- K1: coalesced one-pass band gather, atomic-free global output ----------
__global__ __launch_bounds__(256) void gather_kernel(const float* __restrict__ scores,
                                                     u32* __restrict__ cand,
                                                     int* __restrict__ cnts) {
  __shared__ u32 lkeys[CC * LCAP];
  __shared__ int lcnt[CC];

  int b = blockIdx.x / SLICES;
  int slice = blockIdx.x % SLICES;
  int n0 = slice * ROWS;
  int tid = threadIdx.x;

  if (tid < CC) lcnt[tid] = 0;
  __syncthreads();

  const float4* s4 = (const float4*)scores;
  size_t base4 = ((size_t)b * NN + n0) * (CC / 4);
  for (int i = tid; i < ROWS * (CC / 4); i += 256) {
    float4 q = s4[base4 + i];
    int ib = i * 4;
    float vv[4] = {q.x, q.y, q.z, q.w};
#pragma unroll
    for (int e = 0; e < 4; ++e) {
      float v = vv[e];
      if (v >= BAND_LO) {
        int fe = ib + e;
        int c = fe % CC;
        int n = n0 + fe / CC;
        int s = atomicAdd(&lcnt[c], 1);
        if (s < LCAP)
          lkeys[c * LCAP + s] = ((__float_as_uint(v) - BASEBITS) << 14) | (u32)(16383 - n);
      }
    }
  }
  __syncthreads();

  int bc0 = b * CC;
  if (tid < CC) cnts[(size_t)(bc0 + tid) * SLICES + slice] = lcnt[tid];
  for (int idx = tid; idx < CC * LCAP; idx += 256) {
    int c = idx / LCAP, i = idx % LCAP;
    int lc = lcnt[c]; if (lc > LCAP) lc = LCAP;
    if (i < lc) cand[((size_t)(bc0 + c) * SLICES + slice) * LCAP + i] = lkeys[idx];
  }
}

// ---------- K2: per-(b,c) hybrid sort + kill-matrix greedy (256 threads) ----------
__global__ __launch_bounds__(256) void nms_kernel(const float* __restrict__ boxes,
                                                  const float* __restrict__ scores,
                                                  const u32* __restrict__ cand,
                                                  const int* __restrict__ cnts,
                                                  float* __restrict__ det_score,
                                                  float* __restrict__ det_box) {
  __shared__ u64 keys[CAP];          // fallback; fast path uses (u32*)keys[0..256)
  __shared__ float sv[CAP];
  __shared__ float4 bxs[CAP];
  __shared__ u64 kcol[MMAX * 4];     // kill columns, 8 KB
  __shared__ float4 abx[TT];
  __shared__ float aarea[TT];
  __shared__ int order_s[TT];
  __shared__ u32 killp[4][64];
  __shared__ int partial[256];
  __shared__ int off_s[SLICES], x_s[SLICES];
  __shared__ int mtot_s, ok_s, nacc_s, cnt_s;

  int bc = blockIdx.x;
  int b = bc / CC, c = bc % CC;
  int tid = threadIdx.x;
  const float* bsrc = boxes + (size_t)b * NN * 4;
  float* dsc = det_score + (size_t)bc * TT;
  float4* dbx = (float4*)det_box + (size_t)bc * TT;
  u32* k32 = (u32*)keys;

  // ---- concat offsets (wave 0 prefix-scan, no atomics)
  if (tid < 64) {
    int craw = cnts[(size_t)bc * SLICES + tid];
    int okl = (craw <= LCAP) ? 1 : 0;
    bool ok = __all(okl);
    int x = (craw > LCAP) ? LCAP : craw;
    int incl = x;
#pragma unroll
    for (int d = 1; d < 64; d <<= 1) {
      int y = __shfl_up(incl, d);
      if (tid >= d) incl += y;
    }
    off_s[tid] = incl - x; x_s[tid] = x;
    if (tid == 63) mtot_s = incl;
    if (tid == 0) { ok_s = ok ? 1 : 0; nacc_s = 0; }
  }
  __syncthreads();
  int m_total = mtot_s;
  bool pre_ok = ok_s && (m_total <= MMAX);
  if (pre_ok) {
    int slice = tid >> 2, li = tid & 3;
    int x = x_s[slice], off = off_s[slice];
    const u32* seg = cand + ((size_t)bc * SLICES + slice) * LCAP;
    for (int i = li; i < x; i += 4) k32[off + i] = seg[i];
  }
  __syncthreads();

  int nacc = 0;
  float lo, hi;

  if (pre_ok) {
    // ---- fast path: hybrid sort + kill-matrix greedy
    int m = m_total;
    for (int s = m + tid; s < MMAX; s += 256) k32[s] = 0u;   // pad (each tid hits <=1 slot)
    __syncthreads();
    hybrid_sort256_u32(k32, tid);
    if (tid < m) {
      u32 k = k32[tid];
      sv[tid] = __uint_as_float(BASEBITS + (k >> 14));
      u32 n = 16383u - (k & 16383u);
      bxs[tid] = *(const float4*)(bsrc + (size_t)n * 4);
    }
    __syncthreads();
    if (tid < m) {
      float4 bj = bxs[tid];
      float aj = fmaxf(bj.z - bj.x, 0.f) * fmaxf(bj.w - bj.y, 0.f);
#pragma unroll
      for (int w = 0; w < 4; ++w) {
        u64 kw = 0ull;
        int i0 = w << 6, i1 = (m < i0 + 64) ? m : (i0 + 64);
        for (int i = i0; i < i1; ++i) {
          float4 bi = bxs[i];                      // broadcast read
          float ai = fmaxf(bi.z - bi.x, 0.f) * fmaxf(bi.w - bi.y, 0.f);
          float yy1 = fmaxf(bj.x, bi.x), xx1 = fmaxf(bj.y, bi.y);
          float yy2 = fminf(bj.z, bi.z), xx2 = fminf(bj.w, bi.w);
          float inter = fmaxf(yy2 - yy1, 0.f) * fmaxf(xx2 - xx1, 0.f);
          float uni = aj + ai - inter;
          if (i != tid && (inter / fmaxf(uni, 1e-9f) >= 0.5f)) kw |= (1ull << (i - i0));
        }
        kcol[tid * 4 + w] = kw;
      }
    }
    __syncthreads();
    if (tid == 0) {
      u64 live[4];
#pragma unroll
      for (int w = 0; w < 4; ++w) {
        int lo_i = w << 6;
        live[w] = (m <= lo_i) ? 0ull : ((m >= lo_i + 64) ? ~0ull : ((1ull << (m - lo_i)) - 1ull));
      }
      int na = 0;
      while (na < TT) {
        int j;
        if (live[0]) j = __ffsll(live[0]) - 1;
        else if (live[1]) j = 64 + __ffsll(live[1]) - 1;
        else if (live[2]) j = 128 + __ffsll(live[2]) - 1;
        else if (live[3]) j = 192 + __ffsll(live[3]) - 1;
        else break;
        live[j >> 6] &= ~(1ull << (j & 63));
        order_s[na++] = j;
        const u64* kc = &kcol[(size_t)j * 4];
        live[0] &= ~kc[0]; live[1] &= ~kc[1]; live[2] &= ~kc[2]; live[3] &= ~kc[3];
      }
      nacc_s = na;
    }
    __syncthreads();
    nacc = nacc_s;
    if (tid < nacc) {
      int j = order_s[tid];
      float4 bj = bxs[j];
      dsc[tid] = sv[j];
      dbx[tid] = bj;
      abx[tid] = bj;
      aarea[tid] = fmaxf(bj.z - bj.x, 0.f) * fmaxf(bj.w - bj.y, 0.f);
    }
    __syncthreads();
    lo = BAND_LO - 0.03f; if (lo <= 0.31f) lo = 0.0f;
    hi = BAND_LO;
  } else {
    lo = BAND_LO;
    hi = INFINITY;
  }

  // ---- continuation / fallback bands (rare) — R7-proven machinery
  while (nacc < TT && !(pre_ok && hi == BAND_LO && nacc >= TT)) {
    if (pre_ok && nacc >= TT) break;
    if (nacc >= TT) break;
    if (pre_ok && lo > hi) break;   // (defensive; not reachable)
    // rescan band [lo, hi)
    float band_lo = lo;
    int m;
    for (int tries = 0;; ++tries) {
      if (tid == 0) cnt_s = 0;
      __syncthreads();
      for (int n = tid; n < NN; n += 256) {
        float v = scores[((size_t)b * NN + n) * CC + c];
        if (v > 0.3f && v >= band_lo && v < hi) {
          int s = atomicAdd(&cnt_s, 1);
          if (s < CAP) keys[s] = ((u64)__float_as_uint(v) << 32) | (u32)(~(u32)n);
        }
      }
      __syncthreads();
      if (cnt_s <= CAP || tries >= 24) break;
      float hi_eff = (hi > 1.0f) ? 1.0f : hi;
      band_lo = 0.5f * (band_lo + hi_eff);
      __syncthreads();
    }
    m = (cnt_s < CAP) ? cnt_s : CAP;
    lo = band_lo;                     // consumed band = [band_lo, hi)

    if (m > 0) {
      int n2 = 64; while (n2 < m) n2 <<= 1;
      for (int s = m + tid; s < n2; s += 256) keys[s] = 0ull;
      __syncthreads();
      bitonic_desc64(keys, n2, tid);
      for (int s = tid; s < m; s += 256) {
        u64 k = keys[s];
        sv[s] = __uint_as_float((u32)(k >> 32));
        u32 n = ~(u32)k;
        bxs[s] = *(const float4*)(bsrc + (size_t)n * 4);
      }
      __syncthreads();

      // chunked-ballot greedy (R7)
      int nchunks = (m + 63) >> 6;
      int j = tid & 63, blk = tid >> 6;
      for (int ch = 0; ch < nchunks; ++ch) {
        int na = nacc_s;
        if (na >= TT) break;
        int sj = ch * 64 + j;
        bool have = sj < m;
        float4 bj = have ? bxs[sj] : make_float4(0.f, 0.f, 0.f, 0.f);
        float aj = fmaxf(bj.z - bj.x, 0.f) * fmaxf(bj.w - bj.y, 0.f);

        int dead = have ? 0 : 1;
        for (int a = blk; a < na; a += 4) {
          float4 ab = abx[a]; float aa = aarea[a];
          float yy1 = fmaxf(ab.x, bj.x), xx1 = fmaxf(ab.y, bj.y);
          float yy2 = fminf(ab.z, bj.z), xx2 = fminf(ab.w, bj.w);
          float inter = fmaxf(yy2 - yy1, 0.f) * fmaxf(xx2 - xx1, 0.f);
          float uni = aa + aj - inter;
          if (inter / fmaxf(uni, 1e-9f) >= 0.5f) dead = 1;
        }
        partial[tid] = dead;

        u32 kp = 0;
#pragma unroll
        for (int r = 0; r < 16; ++r) {
          int i = blk * 16 + r;
          float4 bi = bxs[ch * 64 + i];
          float ai = fmaxf(bi.z - bi.x, 0.f) * fmaxf(bi.w - bi.y, 0.f);
          float yy1 = fmaxf(bj.x, bi.x), xx1 = fmaxf(bj.y, bi.y);
          float yy2 = fminf(bj.z, bi.z), xx2 = fminf(bj.w, bi.w);
          float inter = fmaxf(yy2 - yy1, 0.f) * fmaxf(xx2 - xx1, 0.f);
          float uni = aj + ai - inter;
          if (i > j && (inter / fmaxf(uni, 1e-9f) >= 0.5f)) kp |= (1u << r);
        }
        killp[blk][j] = kp;
        __syncthreads();

        if (tid < 64) {
          int l = tid;
          int d0 = partial[l] | partial[64 + l] | partial[128 + l] | partial[192 + l];
          u32 klo = killp[0][l] | (killp[1][l] << 16);
          u32 khi = killp[2][l] | (killp[3][l] << 16);
          u64 deadm = __ballot(d0 != 0);
          u64 accb = 0ull;
          int space = TT - na;
          for (int jj = 0; jj < 64; ++jj) {
            if (!((deadm >> jj) & 1ull)) {
              accb |= (1ull << jj);
              if ((int)__popcll(accb) >= space) break;
              u64 kj = ((u64)(u32)__shfl((int)klo, jj)) |
                       (((u64)(u32)__shfl((int)khi, jj)) << 32);
              deadm |= kj;
            }
          }
          bool accme = ((accb >> l) & 1ull) != 0;
          if (accme) {
            int rank = __popcll(accb & ((1ull << l) - 1ull));
            int slot = na + rank;
            abx[slot] = bj; aarea[slot] = aj;
            dsc[slot] = sv[ch * 64 + l];
            dbx[slot] = bj;
          }
          if (l == 0) nacc_s = na + (int)__popcll(accb);
        }
        __syncthreads();
      }
    }

    nacc = nacc_s;
    if (nacc >= TT || lo <= 0.0f) break;
    hi = lo;
    float nlo = lo - 0.03f;
    lo = (nlo <= 0.31f) ? 0.0f : nlo;
    __syncthreads();
  }

  for (int t = nacc + tid; t < TT; t += 256) dsc[t] = -INFINITY;
}

// ---------- K3: per-batch top-100 via threshold-select + hybrid sorts ----------
__global__ __launch_bounds__(256) void topk_select(const float* __restrict__ det_score,
                                                   const float* __restrict__ det_box,
                                                   float* __restrict__ out) {
  __shared__ u64 kk[CC * TT];     // 64 KB
  __shared__ u64 buf[8192];       // 64 KB
  __shared__ int scnt[CC];
  __shared__ int total_s, base_s, vc_s;

  int b = blockIdx.x, tid = threadIdx.x;
  for (int i = tid; i < CC * TT; i += 256) {
    float v = det_score[(size_t)b * CC * TT + i];
    kk[i] = (v == -INFINITY) ? 0ull : (((u64)__float_as_uint(v) << 32) | (u32)(~(u32)i));
  }
  if (tid == 0) { total_s = 0; base_s = 0; vc_s = 0; }
  __syncthreads();

  // threshold from per-class top-2
  buf[tid] = (tid < 2 * CC) ? kk[(tid >> 1) * TT + (tid & 1)] : 0ull;
  __syncthreads();
  hybrid_sort256_u64(buf, tid);
  u64 t = buf[99];
  u64 tq = t ? t : 1ull;
  __syncthreads();

  if (tid < CC) {
    int lo2 = 0, hi2 = TT;
    while (lo2 < hi2) {
      int mid = (lo2 + hi2) >> 1;
      if (kk[tid * TT + mid] >= tq) lo2 = mid + 1; else hi2 = mid;
    }
    scnt[tid] = lo2;
    atomicAdd(&total_s, lo2);
  }
  __syncthreads();
  int total = total_s;
  int n2 = 256;
  while (n2 < total) n2 <<= 1;

  if (tid < CC) {
    int m = scnt[tid];
    int gb = atomicAdd(&base_s, m);
    for (int i = 0; i < m; ++i) buf[gb + i] = kk[tid * TT + i];
  }
  __syncthreads();
  for (int i = total + tid; i < n2; i += 256) buf[i] = 0ull;
  __syncthreads();
  if (n2 == 256) hybrid_sort256_u64(buf, tid);
  else bitonic_desc64(buf, n2, tid);

  float* ob = out + (size_t)b * TT * 4;            // [0,3200)
  float* os = out + BB * TT * 4 + (size_t)b * TT;  // [3200,4000)
  float* ol = out + BB * TT * 5 + (size_t)b * TT;  // [4000,4800)
  if (tid < TT) {
    u64 k = buf[tid];
    bool valid = (k != 0ull);
    u32 j = valid ? (u32)(~(u32)k) : 0u;
    float v = __uint_as_float((u32)(k >> 32));
    float4 bx = make_float4(0.f, 0.f, 0.f, 0.f);
    if (valid) bx = *(const float4*)(det_box + ((size_t)b * CC * TT + j) * 4);
    ((float4*)ob)[tid] = bx;
    os[tid] = valid ? v : 0.0f;
    ol[tid] = valid ? (float)(j / TT) : 0.0f;
    if (valid) atomicAdd(&vc_s, 1);
  }
  __syncthreads();
  if (tid == 0) out[BB * TT * 5 + BB * TT + b] = (float)vc_s;
}

// ---------- launch ----------
extern "C" void kernel_launch(void* const* d_in, const int* in_sizes, int n_in,
                              void* d_out, int out_size, void* d_ws, size_t ws_size,
                              hipStream_t stream) {
  const float* boxes  = (const float*)d_in[0];   // (8,16384,4)
  const float* scores = (const float*)d_in[1];   // (8,16384,80)
  float* out = (float*)d_out;                    // 4808 floats

  char* ws = (char*)d_ws;
  const size_t CAND_B = (size_t)BB * CC * SLICES * LCAP * 4;  // 3,932,160
  const size_t CNTS_B = (size_t)BB * CC * SLICES * 4;         //   163,840
  const size_t DBX_B  = (size_t)BB * CC * TT * 16;            // 1,024,000
  u32*   cand      = (u32*)ws;
  int*   cnts      = (int*)(ws + CAND_B);
  float* det_box   = (float*)(ws + CAND_B + CNTS_B);
  float* det_score = (float*)(ws + CAND_B + CNTS_B + DBX_B);

  gather_kernel<<<BB * SLICES, 256, 0, stream>>>(scores, cand, cnts);
  nms_kernel<<<BB * CC, 256, 0, stream>>>(boxes, scores, cand, cnts, det_score, det_box);
  topk_select<<<BB, 256, 0, stream>>>(det_score, det_box, out);
}

// Round 9
// 133.464 us; speedup vs baseline: 1.3111x; 1.3111x over previous
//
#include <hip/hip_runtime.h>
#include <math.h>
#include <stdint.h>

#define BB 8
#define NN 16384
#define CC 80
#define TT 100
#define CAP 1024
#define MMAX 256                 // fast-path candidate cap
#define BAND_LO 0.98828125f      // 1 - 3/256
#define BASEBITS 0x3F7D0000u     // __float_as_uint(BAND_LO)
#define LCAP 24                  // per-slice per-class cap (E=3)
#define SLICES 64
#define ROWS 256                 // NN / SLICES

typedef unsigned int u32;
typedef unsigned long long u64;

__device__ __forceinline__ u64 shfl_xor_u64(u64 v, int m) {
  int lo = __shfl_xor((int)(u32)v, m);
  int hi = __shfl_xor((int)(v >> 32), m);
  return ((u64)(u32)hi << 32) | (u32)lo;
}

// plain LDS bitonic (descending), 256 threads, any pow2 n2
__device__ __forceinline__ void bitonic_desc64(u64* buf, int n2, int tid) {
  for (int k = 2; k <= n2; k <<= 1)
    for (int j = k >> 1; j > 0; j >>= 1) {
      for (int i = tid; i < n2; i += 256) {
        int ixj = i ^ j;
        if (ixj > i) {
          u64 a = buf[i], d2 = buf[ixj];
          bool up = ((i & k) == 0);
          if (up ? (a < d2) : (a > d2)) { buf[i] = d2; buf[ixj] = a; }
        }
      }
      __syncthreads();
    }
}

// hybrid shfl/LDS bitonic over exactly 256 elements, 256 threads (descending)
__device__ __forceinline__ void hybrid_sort256_u64(u64* buf, int tid) {
  u64 r = buf[tid];
  for (int k = 2; k <= 256; k <<= 1)
    for (int j = k >> 1; j > 0; j >>= 1) {
      int keep_max = (((tid & k) == 0) == ((tid & j) == 0));
      u64 other;
      if (j >= 64) { __syncthreads(); buf[tid] = r; __syncthreads(); other = buf[tid ^ j]; }
      else other = shfl_xor_u64(r, j);
      u64 mx = (r > other) ? r : other, mn = (r > other) ? other : r;
      r = keep_max ? mx : mn;
    }
  __syncthreads(); buf[tid] = r; __syncthreads();
}

__device__ __forceinline__ void hybrid_sort256_u32(u32* buf, int tid) {
  u32 r = buf[tid];
  for (int k = 2; k <= 256; k <<= 1)
    for (int j = k >> 1; j > 0; j >>= 1) {
      int keep_max = (((tid & k) == 0) == ((tid & j) == 0));
      u32 other;
      if (j >= 64) { __syncthreads(); buf[tid] = r; __syncthreads(); other = buf[tid ^ j]; }
      else other = __shfl_xor(r, j);
      u32 mx = (r > other) ? r : other, mn = (r > other) ? other : r;
      r = keep_max ? mx : mn;
    }
  __syncthreads(); buf[tid] = r; __syncthreads();
}

// ---------- K1: coalesced one-pass band gather, atomic-free global output ----------
__global__ __launch_bounds__(256) void gather_kernel(const float* __restrict__ scores,
                                                     u32* __restrict__ cand,
                                                     int* __restrict__ cnts) {
  __shared__ u32 lkeys[CC * LCAP];
  __shared__ int lcnt[CC];

  int b = blockIdx.x / SLICES;
  int slice = blockIdx.x % SLICES;
  int n0 = slice * ROWS;
  int tid = threadIdx.x;

  if (tid < CC) lcnt[tid] = 0;
  __syncthreads();

  const float4* s4 = (const float4*)scores;
  size_t base4 = ((size_t)b * NN + n0) * (CC / 4);
  for (int i = tid; i < ROWS * (CC / 4); i += 256) {
    float4 q = s4[base4 + i];
    int ib = i * 4;
    float vv[4] = {q.x, q.y, q.z, q.w};
#pragma unroll
    for (int e = 0; e < 4; ++e) {
      float v = vv[e];
      if (v >= BAND_LO) {
        int fe = ib + e;
        int c = fe % CC;
        int n = n0 + fe / CC;
        int s = atomicAdd(&lcnt[c], 1);
        if (s < LCAP)
          lkeys[c * LCAP + s] = ((__float_as_uint(v) - BASEBITS) << 14) | (u32)(16383 - n);
      }
    }
  }
  __syncthreads();

  int bc0 = b * CC;
  if (tid < CC) cnts[(size_t)(bc0 + tid) * SLICES + slice] = lcnt[tid];
  for (int idx = tid; idx < CC * LCAP; idx += 256) {
    int c = idx / LCAP, i = idx % LCAP;
    int lc = lcnt[c]; if (lc > LCAP) lc = LCAP;
    if (i < lc) cand[((size_t)(bc0 + c) * SLICES + slice) * LCAP + i] = lkeys[idx];
  }
}

// ---------- K2: per-(b,c) hybrid sort + chunked-ballot greedy (256 threads) ----------
__global__ __launch_bounds__(256) void nms_kernel(const float* __restrict__ boxes,
                                                  const float* __restrict__ scores,
                                                  const u32* __restrict__ cand,
                                                  const int* __restrict__ cnts,
                                                  float* __restrict__ det_score,
                                                  float* __restrict__ det_box) {
  __shared__ u64 keys[CAP];          // 8 KB; fast path uses (u32*)keys[0..256)
  __shared__ float sv[CAP];          // 4 KB sorted scores
  __shared__ float4 bxs[CAP];        // 16 KB sorted boxes
  __shared__ float car[CAP];         // 4 KB sorted candidate areas
  __shared__ float4 abx[TT];         // accepted boxes
  __shared__ float aarea[TT];
  __shared__ u32 killp[4][64];
  __shared__ int partial[256];
  __shared__ int off_s[SLICES], x_s[SLICES];
  __shared__ int mtot_s, ok_s, nacc_s, cnt_s;

  int bc = blockIdx.x;
  int b = bc / CC, c = bc % CC;
  int tid = threadIdx.x;
  const float* bsrc = boxes + (size_t)b * NN * 4;
  float* dsc = det_score + (size_t)bc * TT;
  float4* dbx = (float4*)det_box + (size_t)bc * TT;
  u32* k32 = (u32*)keys;

  // ---- concat offsets (wave 0 prefix-scan, no atomics)
  if (tid < 64) {
    int craw = cnts[(size_t)bc * SLICES + tid];
    int okl = (craw <= LCAP) ? 1 : 0;
    bool ok = __all(okl);
    int x = (craw > LCAP) ? LCAP : craw;
    int incl = x;
#pragma unroll
    for (int d = 1; d < 64; d <<= 1) {
      int y = __shfl_up(incl, d);
      if (tid >= d) incl += y;
    }
    off_s[tid] = incl - x; x_s[tid] = x;
    if (tid == 63) mtot_s = incl;
    if (tid == 0) { ok_s = ok ? 1 : 0; nacc_s = 0; }
  }
  __syncthreads();
  int m_total = mtot_s;
  bool pre_ok = ok_s && (m_total <= MMAX);
  if (pre_ok) {
    int slice = tid >> 2, li = tid & 3;
    int x = x_s[slice], off = off_s[slice];
    const u32* seg = cand + ((size_t)bc * SLICES + slice) * LCAP;
    for (int i = li; i < x; i += 4) k32[off + i] = seg[i];
  }
  __syncthreads();

  float lo = BAND_LO, hi = INFINITY;
  bool first = true;
  int nacc = 0;

  for (;;) {
    // ---- build sorted candidate arrays sv/bxs/car for this band
    int m;
    bool fast = first && pre_ok;
    if (fast) {
      m = m_total;
      for (int s = m + tid; s < MMAX; s += 256) k32[s] = 0u;   // pad (<=1 slot per tid)
      __syncthreads();
      hybrid_sort256_u32(k32, tid);
      if (tid < m) {
        u32 k = k32[tid];
        sv[tid] = __uint_as_float(BASEBITS + (k >> 14));
        u32 n = 16383u - (k & 16383u);
        float4 bx = *(const float4*)(bsrc + (size_t)n * 4);
        bxs[tid] = bx;
        car[tid] = fmaxf(bx.z - bx.x, 0.f) * fmaxf(bx.w - bx.y, 0.f);
      }
      __syncthreads();
    } else {
      float band_lo = lo;
      for (int tries = 0;; ++tries) {
        if (tid == 0) cnt_s = 0;
        __syncthreads();
        for (int n = tid; n < NN; n += 256) {
          float v = scores[((size_t)b * NN + n) * CC + c];
          if (v > 0.3f && v >= band_lo && v < hi) {
            int s = atomicAdd(&cnt_s, 1);
            if (s < CAP) keys[s] = ((u64)__float_as_uint(v) << 32) | (u32)(~(u32)n);
          }
        }
        __syncthreads();
        if (cnt_s <= CAP || tries >= 24) break;
        float hi_eff = (hi > 1.0f) ? 1.0f : hi;
        band_lo = 0.5f * (band_lo + hi_eff);
        __syncthreads();
      }
      m = (cnt_s < CAP) ? cnt_s : CAP;
      lo = band_lo;                   // consumed band = [band_lo, hi)
      if (m > 0) {
        int n2 = 64; while (n2 < m) n2 <<= 1;
        for (int s = m + tid; s < n2; s += 256) keys[s] = 0ull;
        __syncthreads();
        bitonic_desc64(keys, n2, tid);
        for (int s = tid; s < m; s += 256) {
          u64 k = keys[s];
          sv[s] = __uint_as_float((u32)(k >> 32));
          u32 n = ~(u32)k;
          float4 bx = *(const float4*)(bsrc + (size_t)n * 4);
          bxs[s] = bx;
          car[s] = fmaxf(bx.z - bx.x, 0.f) * fmaxf(bx.w - bx.y, 0.f);
        }
        __syncthreads();
      }
    }
    first = false;

    // ---- chunked-ballot greedy (exactly mirrors serial order)
    if (m > 0) {
      int nchunks = (m + 63) >> 6;
      int j = tid & 63, blk = tid >> 6;
      for (int ch = 0; ch < nchunks; ++ch) {
        int na = nacc_s;
        if (na >= TT) break;
        int sj = ch * 64 + j;
        bool have = sj < m;
        float4 bj = have ? bxs[sj] : make_float4(0.f, 0.f, 0.f, 0.f);
        float aj = have ? car[sj] : 0.f;

        // suppression vs accepted set, 4-way split over blk
        int dead = have ? 0 : 1;
        for (int a = blk; a < na; a += 4) {
          float4 ab = abx[a]; float aa = aarea[a];
          float yy1 = fmaxf(ab.x, bj.x), xx1 = fmaxf(ab.y, bj.y);
          float yy2 = fminf(ab.z, bj.z), xx2 = fminf(ab.w, bj.w);
          float inter = fmaxf(yy2 - yy1, 0.f) * fmaxf(xx2 - xx1, 0.f);
          float uni = aa + aj - inter;
          if (inter / fmaxf(uni, 1e-9f) >= 0.5f) dead = 1;
        }
        partial[tid] = dead;

        // kill matrix: j kills i (i > j), 16 victims per thread
        u32 kp = 0;
#pragma unroll
        for (int r = 0; r < 16; ++r) {
          int i = blk * 16 + r;
          float4 bi = bxs[ch * 64 + i];
          float ai = car[ch * 64 + i];
          float yy1 = fmaxf(bj.x, bi.x), xx1 = fmaxf(bj.y, bi.y);
          float yy2 = fminf(bj.z, bi.z), xx2 = fminf(bj.w, bi.w);
          float inter = fmaxf(yy2 - yy1, 0.f) * fmaxf(xx2 - xx1, 0.f);
          float uni = aj + ai - inter;
          if (i > j && (inter / fmaxf(uni, 1e-9f) >= 0.5f)) kp |= (1u << r);
        }
        killp[blk][j] = kp;
        __syncthreads();

        // wave-0 in-register resolution
        if (tid < 64) {
          int l = tid;
          int d0 = partial[l] | partial[64 + l] | partial[128 + l] | partial[192 + l];
          u32 klo = killp[0][l] | (killp[1][l] << 16);
          u32 khi = killp[2][l] | (killp[3][l] << 16);
          u64 deadm = __ballot(d0 != 0);
          u64 accb = 0ull;
          int space = TT - na;
          for (int jj = 0; jj < 64; ++jj) {
            if (!((deadm >> jj) & 1ull)) {
              accb |= (1ull << jj);
              if ((int)__popcll(accb) >= space) break;
              u64 kj = ((u64)(u32)__shfl((int)klo, jj)) |
                       (((u64)(u32)__shfl((int)khi, jj)) << 32);
              deadm |= kj;
            }
          }
          bool accme = ((accb >> l) & 1ull) != 0;
          if (accme) {
            int rank = __popcll(accb & ((1ull << l) - 1ull));
            int slot = na + rank;
            abx[slot] = bj; aarea[slot] = aj;
            dsc[slot] = sv[ch * 64 + l];
            dbx[slot] = bj;
          }
          if (l == 0) nacc_s = na + (int)__popcll(accb);
        }
        __syncthreads();
      }
    }

    nacc = nacc_s;
    if (nacc >= TT || lo <= 0.0f) break;
    hi = lo;
    float nlo = lo - 0.03f;
    lo = (nlo <= 0.31f) ? 0.0f : nlo;
    __syncthreads();
  }
  // sentinels
  for (int t = nacc + tid; t < TT; t += 256) dsc[t] = -INFINITY;
}

// ---------- K3: per-batch top-100 via threshold-select + hybrid sorts ----------
__global__ __launch_bounds__(256) void topk_select(const float* __restrict__ det_score,
                                                   const float* __restrict__ det_box,
                                                   float* __restrict__ out) {
  __shared__ u64 kk[CC * TT];     // 64 KB
  __shared__ u64 buf[8192];       // 64 KB
  __shared__ int scnt[CC];
  __shared__ int total_s, base_s, vc_s;

  int b = blockIdx.x, tid = threadIdx.x;
  for (int i = tid; i < CC * TT; i += 256) {
    float v = det_score[(size_t)b * CC * TT + i];
    kk[i] = (v == -INFINITY) ? 0ull : (((u64)__float_as_uint(v) << 32) | (u32)(~(u32)i));
  }
  if (tid == 0) { total_s = 0; base_s = 0; vc_s = 0; }
  __syncthreads();

  // threshold from per-class top-2 (subset => t <= t100 => superset gathered)
  buf[tid] = (tid < 2 * CC) ? kk[(tid >> 1) * TT + (tid & 1)] : 0ull;
  __syncthreads();
  hybrid_sort256_u64(buf, tid);
  u64 t = buf[99];
  u64 tq = t ? t : 1ull;
  __syncthreads();

  if (tid < CC) {
    int lo2 = 0, hi2 = TT;
    while (lo2 < hi2) {
      int mid = (lo2 + hi2) >> 1;
      if (kk[tid * TT + mid] >= tq) lo2 = mid + 1; else hi2 = mid;
    }
    scnt[tid] = lo2;
    atomicAdd(&total_s, lo2);
  }
  __syncthreads();
  int total = total_s;
  int n2 = 256;
  while (n2 < total) n2 <<= 1;

  if (tid < CC) {
    int m = scnt[tid];
    int gb = atomicAdd(&base_s, m);
    for (int i = 0; i < m; ++i) buf[gb + i] = kk[tid * TT + i];
  }
  __syncthreads();
  for (int i = total + tid; i < n2; i += 256) buf[i] = 0ull;
  __syncthreads();
  if (n2 == 256) hybrid_sort256_u64(buf, tid);
  else bitonic_desc64(buf, n2, tid);

  float* ob = out + (size_t)b * TT * 4;            // [0,3200)
  float* os = out + BB * TT * 4 + (size_t)b * TT;  // [3200,4000)
  float* ol = out + BB * TT * 5 + (size_t)b * TT;  // [4000,4800)
  if (tid < TT) {
    u64 k = buf[tid];
    bool valid = (k != 0ull);
    u32 j = valid ? (u32)(~(u32)k) : 0u;
    float v = __uint_as_float((u32)(k >> 32));
    float4 bx = make_float4(0.f, 0.f, 0.f, 0.f);
    if (valid) bx = *(const float4*)(det_box + ((size_t)b * CC * TT + j) * 4);
    ((float4*)ob)[tid] = bx;
    os[tid] = valid ? v : 0.0f;
    ol[tid] = valid ? (float)(j / TT) : 0.0f;
    if (valid) atomicAdd(&vc_s, 1);
  }
  __syncthreads();
  if (tid == 0) out[BB * TT * 5 + BB * TT + b] = (float)vc_s;
}

// ---------- launch ----------
extern "C" void kernel_launch(void* const* d_in, const int* in_sizes, int n_in,
                              void* d_out, int out_size, void* d_ws, size_t ws_size,
                              hipStream_t stream) {
  const float* boxes  = (const float*)d_in[0];   // (8,16384,4)
  const float* scores = (const float*)d_in[1];   // (8,16384,80)
  float* out = (float*)d_out;                    // 4808 floats

  char* ws = (char*)d_ws;
  const size_t CAND_B = (size_t)BB * CC * SLICES * LCAP * 4;  // 3,932,160
  const size_t CNTS_B = (size_t)BB * CC * SLICES * 4;         //   163,840
  const size_t DBX_B  = (size_t)BB * CC * TT * 16;            // 1,024,000
  u32*   cand      = (u32*)ws;
  int*   cnts      = (int*)(ws + CAND_B);
  float* det_box   = (float*)(ws + CAND_B + CNTS_B);
  float* det_score = (float*)(ws + CAND_B + CNTS_B + DBX_B);

  gather_kernel<<<BB * SLICES, 256, 0, stream>>>(scores, cand, cnts);
  nms_kernel<<<BB * CC, 256, 0, stream>>>(boxes, scores, cand, cnts, det_score, det_box);
  topk_select<<<BB, 256, 0, stream>>>(det_score, det_box, out);
}

// Round 10
// 130.208 us; speedup vs baseline: 1.3439x; 1.0250x over previous
//
#include <hip/hip_runtime.h>
#include <math.h>
#include <stdint.h>

#define BB 8
#define NN 16384
#define CC 80
#define TT 100
#define CAP 512                  // fallback candidate cap (band-halving keeps exactness)
#define MMAX 256                 // fast-path candidate cap
#define BAND_LO 0.98828125f      // 1 - 3/256
#define BASEBITS 0x3F7D0000u     // __float_as_uint(BAND_LO)
#define LCAP 16                  // per-slice per-class cap (E=1.5)
#define SLICES 128
#define ROWS 128                 // NN / SLICES

typedef unsigned int u32;
typedef unsigned long long u64;

__device__ __forceinline__ u64 shfl_xor_u64(u64 v, int m) {
  int lo = __shfl_xor((int)(u32)v, m);
  int hi = __shfl_xor((int)(v >> 32), m);
  return ((u64)(u32)hi << 32) | (u32)lo;
}

// plain LDS bitonic (descending), 256 threads, any pow2 n2
__device__ __forceinline__ void bitonic_desc64(u64* buf, int n2, int tid) {
  for (int k = 2; k <= n2; k <<= 1)
    for (int j = k >> 1; j > 0; j >>= 1) {
      for (int i = tid; i < n2; i += 256) {
        int ixj = i ^ j;
        if (ixj > i) {
          u64 a = buf[i], d2 = buf[ixj];
          bool up = ((i & k) == 0);
          if (up ? (a < d2) : (a > d2)) { buf[i] = d2; buf[ixj] = a; }
        }
      }
      __syncthreads();
    }
}

// hybrid shfl/LDS bitonic over exactly 256 elements, 256 threads (descending)
__device__ __forceinline__ void hybrid_sort256_u64(u64* buf, int tid) {
  u64 r = buf[tid];
  for (int k = 2; k <= 256; k <<= 1)
    for (int j = k >> 1; j > 0; j >>= 1) {
      int keep_max = (((tid & k) == 0) == ((tid & j) == 0));
      u64 other;
      if (j >= 64) { __syncthreads(); buf[tid] = r; __syncthreads(); other = buf[tid ^ j]; }
      else other = shfl_xor_u64(r, j);
      u64 mx = (r > other) ? r : other, mn = (r > other) ? other : r;
      r = keep_max ? mx : mn;
    }
  __syncthreads(); buf[tid] = r; __syncthreads();
}

__device__ __forceinline__ void hybrid_sort256_u32(u32* buf, int tid) {
  u32 r = buf[tid];
  for (int k = 2; k <= 256; k <<= 1)
    for (int j = k >> 1; j > 0; j >>= 1) {
      int keep_max = (((tid & k) == 0) == ((tid & j) == 0));
      u32 other;
      if (j >= 64) { __syncthreads(); buf[tid] = r; __syncthreads(); other = buf[tid ^ j]; }
      else other = __shfl_xor(r, j);
      u32 mx = (r > other) ? r : other, mn = (r > other) ? other : r;
      r = keep_max ? mx : mn;
    }
  __syncthreads(); buf[tid] = r; __syncthreads();
}

// ---------- K1: coalesced one-pass band gather, atomic-free global output ----------
__global__ __launch_bounds__(256) void gather_kernel(const float* __restrict__ scores,
                                                     u32* __restrict__ cand,
                                                     int* __restrict__ cnts) {
  __shared__ u32 lkeys[CC * LCAP];   // 5 KB
  __shared__ int lcnt[CC];

  int b = blockIdx.x / SLICES;
  int slice = blockIdx.x % SLICES;
  int n0 = slice * ROWS;
  int tid = threadIdx.x;

  if (tid < CC) lcnt[tid] = 0;
  __syncthreads();

  const float4* s4 = (const float4*)scores;
  size_t base4 = ((size_t)b * NN + n0) * (CC / 4);
  for (int i = tid; i < ROWS * (CC / 4); i += 256) {
    float4 q = s4[base4 + i];
    int ib = i * 4;
    float vv[4] = {q.x, q.y, q.z, q.w};
#pragma unroll
    for (int e = 0; e < 4; ++e) {
      float v = vv[e];
      if (v >= BAND_LO) {
        int fe = ib + e;
        int c = fe % CC;
        int n = n0 + fe / CC;
        int s = atomicAdd(&lcnt[c], 1);
        if (s < LCAP)
          lkeys[(c << 4) + s] = ((__float_as_uint(v) - BASEBITS) << 14) | (u32)(16383 - n);
      }
    }
  }
  __syncthreads();

  int bc0 = b * CC;
  if (tid < CC) cnts[(size_t)(bc0 + tid) * SLICES + slice] = lcnt[tid];
  for (int idx = tid; idx < CC * LCAP; idx += 256) {
    int c = idx >> 4, i = idx & 15;
    int lc = lcnt[c]; if (lc > LCAP) lc = LCAP;
    if (i < lc) cand[((size_t)(bc0 + c) * SLICES + slice) * LCAP + i] = lkeys[idx];
  }
}

// ---------- K2: per-(b,c) hybrid sort + chunked-ballot greedy (256 threads) ----------
__global__ __launch_bounds__(256) void nms_kernel(const float* __restrict__ boxes,
                                                  const float* __restrict__ scores,
                                                  const u32* __restrict__ cand,
                                                  const int* __restrict__ cnts,
                                                  float* __restrict__ det_score,
                                                  float* __restrict__ det_box) {
  __shared__ u64 keys[CAP];          // 4 KB; fast path uses (u32*)keys[0..256)
  __shared__ float sv[CAP];          // 2 KB
  __shared__ float4 bxs[CAP];        // 8 KB
  __shared__ float car[CAP];         // 2 KB
  __shared__ float4 abx[TT];
  __shared__ float aarea[TT];
  __shared__ u32 killp[4][64];
  __shared__ int partial[256];
  __shared__ int off_s[SLICES], x_s[SLICES];
  __shared__ int mtot_s, ok_s, nacc_s, cnt_s;

  int bc = blockIdx.x;
  int b = bc / CC, c = bc % CC;
  int tid = threadIdx.x;
  const float* bsrc = boxes + (size_t)b * NN * 4;
  float* dsc = det_score + (size_t)bc * TT;
  float4* dbx = (float4*)det_box + (size_t)bc * TT;
  u32* k32 = (u32*)keys;

  // ---- concat offsets: 128 segments, 2 per lane, wave-0 prefix-scan
  if (tid < 64) {
    int s0 = 2 * tid, s1 = 2 * tid + 1;
    int c0 = cnts[(size_t)bc * SLICES + s0];
    int c1 = cnts[(size_t)bc * SLICES + s1];
    int okl = (c0 <= LCAP && c1 <= LCAP) ? 1 : 0;
    bool ok = __all(okl);
    int x0 = (c0 > LCAP) ? LCAP : c0;
    int x1 = (c1 > LCAP) ? LCAP : c1;
    int x = x0 + x1;
    int incl = x;
#pragma unroll
    for (int d = 1; d < 64; d <<= 1) {
      int y = __shfl_up(incl, d);
      if (tid >= d) incl += y;
    }
    int off = incl - x;
    off_s[s0] = off; off_s[s1] = off + x0;
    x_s[s0] = x0; x_s[s1] = x1;
    if (tid == 63) mtot_s = incl;
    if (tid == 0) { ok_s = ok ? 1 : 0; nacc_s = 0; }
  }
  __syncthreads();
  int m_total = mtot_s;
  bool pre_ok = ok_s && (m_total <= MMAX);
  if (pre_ok) {
    int slice = tid >> 1, li = tid & 1;
    int x = x_s[slice], off = off_s[slice];
    const u32* seg = cand + ((size_t)bc * SLICES + slice) * LCAP;
    for (int i = li; i < x; i += 2) k32[off + i] = seg[i];
  }
  __syncthreads();

  float lo = BAND_LO, hi = INFINITY;
  bool first = true;
  int nacc = 0;

  for (;;) {
    // ---- build sorted candidate arrays sv/bxs/car for this band
    int m;
    bool fast = first && pre_ok;
    if (fast) {
      m = m_total;
      for (int s = m + tid; s < MMAX; s += 256) k32[s] = 0u;   // pad (<=1 slot per tid)
      __syncthreads();
      hybrid_sort256_u32(k32, tid);
      if (tid < m) {
        u32 k = k32[tid];
        sv[tid] = __uint_as_float(BASEBITS + (k >> 14));
        u32 n = 16383u - (k & 16383u);
        float4 bx = *(const float4*)(bsrc + (size_t)n * 4);
        bxs[tid] = bx;
        car[tid] = fmaxf(bx.z - bx.x, 0.f) * fmaxf(bx.w - bx.y, 0.f);
      }
      __syncthreads();
    } else {
      float band_lo = lo;
      for (int tries = 0;; ++tries) {
        if (tid == 0) cnt_s = 0;
        __syncthreads();
        for (int n = tid; n < NN; n += 256) {
          float v = scores[((size_t)b * NN + n) * CC + c];
          if (v > 0.3f && v >= band_lo && v < hi) {
            int s = atomicAdd(&cnt_s, 1);
            if (s < CAP) keys[s] = ((u64)__float_as_uint(v) << 32) | (u32)(~(u32)n);
          }
        }
        __syncthreads();
        if (cnt_s <= CAP || tries >= 30) break;
        float hi_eff = (hi > 1.0f) ? 1.0f : hi;
        band_lo = 0.5f * (band_lo + hi_eff);
        __syncthreads();
      }
      m = (cnt_s < CAP) ? cnt_s : CAP;
      lo = band_lo;                   // consumed band = [band_lo, hi)
      if (m > 0) {
        int n2 = 64; while (n2 < m) n2 <<= 1;
        for (int s = m + tid; s < n2; s += 256) keys[s] = 0ull;
        __syncthreads();
        bitonic_desc64(keys, n2, tid);
        for (int s = tid; s < m; s += 256) {
          u64 k = keys[s];
          sv[s] = __uint_as_float((u32)(k >> 32));
          u32 n = ~(u32)k;
          float4 bx = *(const float4*)(bsrc + (size_t)n * 4);
          bxs[s] = bx;
          car[s] = fmaxf(bx.z - bx.x, 0.f) * fmaxf(bx.w - bx.y, 0.f);
        }
        __syncthreads();
      }
    }
    first = false;

    // ---- chunked-ballot greedy (exactly mirrors serial order)
    if (m > 0) {
      int nchunks = (m + 63) >> 6;
      int j = tid & 63, blk = tid >> 6;
      for (int ch = 0; ch < nchunks; ++ch) {
        int na = nacc_s;
        if (na >= TT) break;
        int sj = ch * 64 + j;
        bool have = sj < m;
        float4 bj = have ? bxs[sj] : make_float4(0.f, 0.f, 0.f, 0.f);
        float aj = have ? car[sj] : 0.f;

        // suppression vs accepted set, 4-way split over blk
        int dead = have ? 0 : 1;
        for (int a = blk; a < na; a += 4) {
          float4 ab = abx[a]; float aa = aarea[a];
          float yy1 = fmaxf(ab.x, bj.x), xx1 = fmaxf(ab.y, bj.y);
          float yy2 = fminf(ab.z, bj.z), xx2 = fminf(ab.w, bj.w);
          float inter = fmaxf(yy2 - yy1, 0.f) * fmaxf(xx2 - xx1, 0.f);
          float uni = aa + aj - inter;
          if (inter / fmaxf(uni, 1e-9f) >= 0.5f) dead = 1;
        }
        partial[tid] = dead;

        // kill matrix: j kills i (i > j), 16 victims per thread
        u32 kp = 0;
#pragma unroll
        for (int r = 0; r < 16; ++r) {
          int i = blk * 16 + r;
          float4 bi = bxs[ch * 64 + i];
          float ai = car[ch * 64 + i];
          float yy1 = fmaxf(bj.x, bi.x), xx1 = fmaxf(bj.y, bi.y);
          float yy2 = fminf(bj.z, bi.z), xx2 = fminf(bj.w, bi.w);
          float inter = fmaxf(yy2 - yy1, 0.f) * fmaxf(xx2 - xx1, 0.f);
          float uni = aj + ai - inter;
          if (i > j && (inter / fmaxf(uni, 1e-9f) >= 0.5f)) kp |= (1u << r);
        }
        killp[blk][j] = kp;
        __syncthreads();

        // wave-0 in-register resolution
        if (tid < 64) {
          int l = tid;
          int d0 = partial[l] | partial[64 + l] | partial[128 + l] | partial[192 + l];
          u32 klo = killp[0][l] | (killp[1][l] << 16);
          u32 khi = killp[2][l] | (killp[3][l] << 16);
          u64 deadm = __ballot(d0 != 0);
          u64 accb = 0ull;
          int space = TT - na;
          for (int jj = 0; jj < 64; ++jj) {
            if (!((deadm >> jj) & 1ull)) {
              accb |= (1ull << jj);
              if ((int)__popcll(accb) >= space) break;
              u64 kj = ((u64)(u32)__shfl((int)klo, jj)) |
                       (((u64)(u32)__shfl((int)khi, jj)) << 32);
              deadm |= kj;
            }
          }
          bool accme = ((accb >> l) & 1ull) != 0;
          if (accme) {
            int rank = __popcll(accb & ((1ull << l) - 1ull));
            int slot = na + rank;
            abx[slot] = bj; aarea[slot] = aj;
            dsc[slot] = sv[ch * 64 + l];
            dbx[slot] = bj;
          }
          if (l == 0) nacc_s = na + (int)__popcll(accb);
        }
        __syncthreads();
      }
    }

    nacc = nacc_s;
    if (nacc >= TT || lo <= 0.0f) break;
    hi = lo;
    float nlo = lo - 0.03f;
    lo = (nlo <= 0.31f) ? 0.0f : nlo;
    __syncthreads();
  }
  // sentinels
  for (int t = nacc + tid; t < TT; t += 256) dsc[t] = -INFINITY;
}

// ---------- K3: per-batch top-100 via threshold-select + hybrid sorts ----------
__global__ __launch_bounds__(256) void topk_select(const float* __restrict__ det_score,
                                                   const float* __restrict__ det_box,
                                                   float* __restrict__ out) {
  __shared__ u64 kk[CC * TT];     // 64 KB
  __shared__ u64 buf[8192];       // 64 KB
  __shared__ int scnt[CC];
  __shared__ int total_s, base_s, vc_s;

  int b = blockIdx.x, tid = threadIdx.x;
  for (int i = tid; i < CC * TT; i += 256) {
    float v = det_score[(size_t)b * CC * TT + i];
    kk[i] = (v == -INFINITY) ? 0ull : (((u64)__float_as_uint(v) << 32) | (u32)(~(u32)i));
  }
  if (tid == 0) { total_s = 0; base_s = 0; vc_s = 0; }
  __syncthreads();

  // threshold from per-class top-2 (subset => t <= t100 => superset gathered)
  buf[tid] = (tid < 2 * CC) ? kk[(tid >> 1) * TT + (tid & 1)] : 0ull;
  __syncthreads();
  hybrid_sort256_u64(buf, tid);
  u64 t = buf[99];
  u64 tq = t ? t : 1ull;
  __syncthreads();

  if (tid < CC) {
    int lo2 = 0, hi2 = TT;
    while (lo2 < hi2) {
      int mid = (lo2 + hi2) >> 1;
      if (kk[tid * TT + mid] >= tq) lo2 = mid + 1; else hi2 = mid;
    }
    scnt[tid] = lo2;
    atomicAdd(&total_s, lo2);
  }
  __syncthreads();
  int total = total_s;
  int n2 = 256;
  while (n2 < total) n2 <<= 1;

  if (tid < CC) {
    int m = scnt[tid];
    int gb = atomicAdd(&base_s, m);
    for (int i = 0; i < m; ++i) buf[gb + i] = kk[tid * TT + i];
  }
  __syncthreads();
  for (int i = total + tid; i < n2; i += 256) buf[i] = 0ull;
  __syncthreads();
  if (n2 == 256) hybrid_sort256_u64(buf, tid);
  else bitonic_desc64(buf, n2, tid);

  float* ob = out + (size_t)b * TT * 4;            // [0,3200)
  float* os = out + BB * TT * 4 + (size_t)b * TT;  // [3200,4000)
  float* ol = out + BB * TT * 5 + (size_t)b * TT;  // [4000,4800)
  if (tid < TT) {
    u64 k = buf[tid];
    bool valid = (k != 0ull);
    u32 j = valid ? (u32)(~(u32)k) : 0u;
    float v = __uint_as_float((u32)(k >> 32));
    float4 bx = make_float4(0.f, 0.f, 0.f, 0.f);
    if (valid) bx = *(const float4*)(det_box + ((size_t)b * CC * TT + j) * 4);
    ((float4*)ob)[tid] = bx;
    os[tid] = valid ? v : 0.0f;
    ol[tid] = valid ? (float)(j / TT) : 0.0f;
    if (valid) atomicAdd(&vc_s, 1);
  }
  __syncthreads();
  if (tid == 0) out[BB * TT * 5 + BB * TT + b] = (float)vc_s;
}

// ---------- launch ----------
extern "C" void kernel_launch(void* const* d_in, const int* in_sizes, int n_in,
                              void* d_out, int out_size, void* d_ws, size_t ws_size,
                              hipStream_t stream) {
  const float* boxes  = (const float*)d_in[0];   // (8,16384,4)
  const float* scores = (const float*)d_in[1];   // (8,16384,80)
  float* out = (float*)d_out;                    // 4808 floats

  char* ws = (char*)d_ws;
  const size_t CAND_B = (size_t)BB * CC * SLICES * LCAP * 4;  // 5,242,880
  const size_t CNTS_B = (size_t)BB * CC * SLICES * 4;         //   327,680
  const size_t DBX_B  = (size_t)BB * CC * TT * 16;            // 1,024,000
  u32*   cand      = (u32*)ws;
  int*   cnts      = (int*)(ws + CAND_B);
  float* det_box   = (float*)(ws + CAND_B + CNTS_B);
  float* det_score = (float*)(ws + CAND_B + CNTS_B + DBX_B);

  gather_kernel<<<BB * SLICES, 256, 0, stream>>>(scores, cand, cnts);
  nms_kernel<<<BB * CC, 256, 0, stream>>>(boxes, scores, cand, cnts, det_score, det_box);
  topk_select<<<BB, 256, 0, stream>>>(det_score, det_box, out);
}